// Round 2
// baseline (591.595 us; speedup 1.0000x reference)
//
#include <hip/hip_runtime.h>
#include <hip/hip_bf16.h>

#define NROWS 131072
#define DIM   512
#define NK    64

typedef __attribute__((ext_vector_type(4))) float f32x4;
typedef __attribute__((ext_vector_type(8))) short s16x8;

// pack two fp32 -> one dword of two bf16 (RNE), low half = first arg
static __device__ __forceinline__ unsigned pk2(float a, float b) {
    union { __hip_bfloat162 h; unsigned u; } cv;
    cv.h = __float22bfloat162_rn(make_float2(a, b));
    return cv.u;
}

// --- Kernel 1: L2-normalize clusters (fp32) -> bf16 codebook in ws; zero loss slot.
__global__ void prep_kernel(const float* __restrict__ cl,
                            unsigned* __restrict__ cb,    // bf16[64][512] as dwords
                            float* __restrict__ loss_out) {
    const int k = blockIdx.x, t = threadIdx.x;
    const float4* rp = reinterpret_cast<const float4*>(cl + k * DIM);
    float4 f0 = rp[2 * t], f1 = rp[2 * t + 1];
    float ss = f0.x*f0.x + f0.y*f0.y + f0.z*f0.z + f0.w*f0.w
             + f1.x*f1.x + f1.y*f1.y + f1.z*f1.z + f1.w*f1.w;
#pragma unroll
    for (int m = 1; m < 64; m <<= 1) ss += __shfl_xor(ss, m, 64);
    const float rn = 1.0f / fmaxf(sqrtf(ss), 1e-12f);
    uint4 o;
    o.x = pk2(f0.x * rn, f0.y * rn);
    o.y = pk2(f0.z * rn, f0.w * rn);
    o.z = pk2(f1.x * rn, f1.y * rn);
    o.w = pk2(f1.z * rn, f1.w * rn);
    reinterpret_cast<uint4*>(cb + (size_t)k * (DIM / 2))[t] = o;
    if (k == 0 && t == 0) *loss_out = 0.0f;
}

// --- Kernel 2: fused normalize-x / MFMA GEMM / softmax / loss.
// LDS: 64 KB bf16 codebook ONLY (XOR-swizzled, conflict-free b128 reads).
//   -> 2 blocks/CU, 16 waves/CU (launch_bounds(512,4) caps VGPR at 128).
// v4 changes vs v3:
//   * 256-B-ALIGNED output stores WITHOUT LDS staging: the +1-dword shifted
//     window is produced in registers via __shfl. Store k writes tile
//     elements 64k+lane-1; for fixed k the source is one 16-lane q-group:
//     p[k&3][(lane-1)>>4] of lane ((k>>2)<<4)|((lane-1)&15). v3's direct
//     misaligned stores caused 7x write amplification (246 MB vs 34 MB) +
//     68 MB of output-line RMW fetch -- that was the whole regression.
//   * x prefetch pipeline deepened 2 -> 4 (VGPR headroom at this occupancy).
__global__ __launch_bounds__(512, 4) void fused_kernel(
        const float* __restrict__ x,
        const unsigned* __restrict__ cb,
        const float* __restrict__ alphap,
        float* __restrict__ out) {                 // [0]=loss, [1..]=probs[N][64]
    __shared__ unsigned short ldsb[NK * DIM];      // 64 KB codebook

    // stage codebook: 4096 16B-units; unit c6 of row r stored at (c6 ^ (r&7))
    for (int u = threadIdx.x; u < NK * DIM / 8; u += blockDim.x) {
        const int r = u >> 6, c6 = u & 63;
        const uint4 v = reinterpret_cast<const uint4*>(cb)[u];
        *reinterpret_cast<uint4*>(&ldsb[r * DIM + ((c6 ^ (r & 7)) << 3)]) = v;
    }
    __syncthreads();

    const float alpha = alphap[0];
    const int lane = threadIdx.x & 63;
    const int n = lane & 15;            // A-row / B-col / C-col lane index
    const int q = lane >> 4;            // quad
    const int sw = n & 7;               // LDS unit swizzle for this lane's B rows
    const int gw = (int)((blockIdx.x * blockDim.x + threadIdx.x) >> 6);
    const int nw = (int)((gridDim.x * blockDim.x) >> 6);

    const unsigned short* b_base = &ldsb[n * DIM];

    float lossa = 0.0f;

    for (int g = gw; g < NROWS / 16; g += nw) {
        const int row0 = g << 4;
        const float4* xp4 = reinterpret_cast<const float4*>(
            x + (size_t)(row0 + n) * DIM + (q << 3));
        f32x4 a0 = {0.f,0.f,0.f,0.f}, a1 = {0.f,0.f,0.f,0.f};
        f32x4 a2 = {0.f,0.f,0.f,0.f}, a3 = {0.f,0.f,0.f,0.f};
        float ss = 0.0f;

        // 4-deep register pipeline on x (all indices compile-time constant
        // after full unroll -> no scratch; rule: never runtime-index vectors)
        float4 pf0[4], pf1[4];
#pragma unroll
        for (int j = 0; j < 4; j++) { pf0[j] = xp4[j * 8]; pf1[j] = xp4[j * 8 + 1]; }
#pragma unroll
        for (int t = 0; t < 16; t++) {
            const float4 c0 = pf0[t & 3], c1 = pf1[t & 3];
            if (t < 12) { pf0[t & 3] = xp4[(t + 4) * 8]; pf1[t & 3] = xp4[(t + 4) * 8 + 1]; }
            ss += c0.x*c0.x + c0.y*c0.y + c0.z*c0.z + c0.w*c0.w
                + c1.x*c1.x + c1.y*c1.y + c1.z*c1.z + c1.w*c1.w;
            union { s16x8 v; unsigned u[4]; } A;
            A.u[0] = pk2(c0.x, c0.y); A.u[1] = pk2(c0.z, c0.w);
            A.u[2] = pk2(c1.x, c1.y); A.u[3] = pk2(c1.z, c1.w);
            const int off = (((t << 2) | q) ^ sw) << 3;   // swizzled 16B unit
            const s16x8 b0 = *reinterpret_cast<const s16x8*>(b_base + off);
            const s16x8 b1 = *reinterpret_cast<const s16x8*>(b_base + 16 * DIM + off);
            const s16x8 b2 = *reinterpret_cast<const s16x8*>(b_base + 32 * DIM + off);
            const s16x8 b3 = *reinterpret_cast<const s16x8*>(b_base + 48 * DIM + off);
            a0 = __builtin_amdgcn_mfma_f32_16x16x32_bf16(A.v, b0, a0, 0, 0, 0);
            a1 = __builtin_amdgcn_mfma_f32_16x16x32_bf16(A.v, b1, a1, 0, 0, 0);
            a2 = __builtin_amdgcn_mfma_f32_16x16x32_bf16(A.v, b2, a2, 0, 0, 0);
            a3 = __builtin_amdgcn_mfma_f32_16x16x32_bf16(A.v, b3, a3, 0, 0, 0);
        }

        // finish ||x_row||: lanes (q,n) hold partials of row n
        ss += __shfl_xor(ss, 16, 64);
        ss += __shfl_xor(ss, 32, 64);
        const float rnorm = 1.0f / fmaxf(sqrtf(ss), 1e-12f);

        // p[r][c] = prob of tile row (4q+r), col (n+16c); all const-indexed
        float p[4][4];
#pragma unroll
        for (int r = 0; r < 4; r++) {
            // C row = q*4 + r; its rnorm lives at lanes with (lane&15) == q*4+r
            const float rn = __shfl(rnorm, (q << 2) + r, 64);
            const float i0 = a0[r] * rn, i1 = a1[r] * rn, i2 = a2[r] * rn, i3 = a3[r] * rn;
            const float z0 = i0 * alpha, z1 = i1 * alpha, z2 = i2 * alpha, z3 = i3 * alpha;
            float mx = fmaxf(fmaxf(z0, z1), fmaxf(z2, z3));
#pragma unroll
            for (int m = 1; m < 16; m <<= 1) mx = fmaxf(mx, __shfl_xor(mx, m, 64));
            const float e0 = __expf(z0 - mx), e1 = __expf(z1 - mx);
            const float e2 = __expf(z2 - mx), e3 = __expf(z3 - mx);
            float s  = e0 + e1 + e2 + e3;
            float sl = e0 * i0 + e1 * i1 + e2 * i2 + e3 * i3;   // loss uses pre-alpha ip
#pragma unroll
            for (int m = 1; m < 16; m <<= 1) {
                s  += __shfl_xor(s,  m, 64);
                sl += __shfl_xor(sl, m, 64);
            }
            const float inv = 1.0f / s;
            p[r][0] = e0 * inv;
            p[r][1] = e1 * inv;
            p[r][2] = e2 * inv;
            p[r][3] = e3 * inv;
            if (n == 0) lossa += sl * inv;      // one contribution per row
        }

        // 16 aligned 256-B shifted-window stores, permutation done in-register:
        // out[(row0+k)*64 + lane] = tile element 64k + lane - 1
#pragma unroll
        for (int k = 0; k < 16; k++) {
            const int rs = k & 3;                               // source register row
            const int src = ((k >> 2) << 4) | ((lane - 1) & 15);
            const float t0 = __shfl(p[rs][0], src, 64);
            const float t1 = __shfl(p[rs][1], src, 64);
            const float t2 = __shfl(p[rs][2], src, 64);
            const float t3 = __shfl(p[rs][3], src, 64);
            // lane 0 of store k needs previous tile row's col 63
            const int rp = (k == 0) ? 0 : ((k - 1) & 3);
            const int qp = (k == 0) ? 0 : ((k - 1) >> 2);
            const float tp = __shfl(p[rp][3], (qp << 4) | 15, 64);
            const int cs = ((lane - 1) >> 4) & 3;
            float v = cs == 0 ? t0 : (cs == 1 ? t1 : (cs == 2 ? t2 : t3));
            if (lane == 0) v = tp;
            if (k > 0 || lane > 0)
                out[(size_t)(row0 + k) * 64 + lane] = v;
        }
        // our last element (tile elem 1023 = p[3][3] of lane 63) goes into the
        // next group's first aligned slot
        if (lane == 63)
            out[(size_t)(row0 + 16) * 64] = p[3][3];
    }

    // wave-level loss partials live in lanes 0,16,32,48
    lossa += __shfl_xor(lossa, 16, 64);
    lossa += __shfl_xor(lossa, 32, 64);
    if (lane == 0) atomicAdd(out, -lossa * (1.0f / NROWS));
}

extern "C" void kernel_launch(void* const* d_in, const int* in_sizes, int n_in,
                              void* d_out, int out_size, void* d_ws, size_t ws_size,
                              hipStream_t stream) {
    const float* x  = (const float*)d_in[0];
    const float* cl = (const float*)d_in[1];
    const float* al = (const float*)d_in[2];
    float* out = (float*)d_out;
    unsigned* cb = (unsigned*)d_ws;            // 64 KB bf16 codebook

    prep_kernel<<<dim3(NK), dim3(64), 0, stream>>>(cl, cb, out);
    fused_kernel<<<dim3(512), dim3(512), 0, stream>>>(x, cb, al, out);
}

// Round 4
// 495.765 us; speedup vs baseline: 1.1933x; 1.1933x over previous
//
#include <hip/hip_runtime.h>
#include <hip/hip_bf16.h>

#define NROWS 131072
#define DIM   512
#define NK    64

typedef __attribute__((ext_vector_type(4))) float f32x4;
typedef __attribute__((ext_vector_type(8))) short s16x8;

// pack two fp32 -> one dword of two bf16 (RNE), low half = first arg
static __device__ __forceinline__ unsigned pk2(float a, float b) {
    union { __hip_bfloat162 h; unsigned u; } cv;
    cv.h = __float22bfloat162_rn(make_float2(a, b));
    return cv.u;
}

// --- Kernel 1: L2-normalize clusters (fp32) -> bf16 codebook in ws; zero loss slot.
__global__ void prep_kernel(const float* __restrict__ cl,
                            unsigned* __restrict__ cb,    // bf16[64][512] as dwords
                            float* __restrict__ loss_out) {
    const int k = blockIdx.x, t = threadIdx.x;
    const float4* rp = reinterpret_cast<const float4*>(cl + k * DIM);
    float4 f0 = rp[2 * t], f1 = rp[2 * t + 1];
    float ss = f0.x*f0.x + f0.y*f0.y + f0.z*f0.z + f0.w*f0.w
             + f1.x*f1.x + f1.y*f1.y + f1.z*f1.z + f1.w*f1.w;
#pragma unroll
    for (int m = 1; m < 64; m <<= 1) ss += __shfl_xor(ss, m, 64);
    const float rn = 1.0f / fmaxf(sqrtf(ss), 1e-12f);
    uint4 o;
    o.x = pk2(f0.x * rn, f0.y * rn);
    o.y = pk2(f0.z * rn, f0.w * rn);
    o.z = pk2(f1.x * rn, f1.y * rn);
    o.w = pk2(f1.z * rn, f1.w * rn);
    reinterpret_cast<uint4*>(cb + (size_t)k * (DIM / 2))[t] = o;
    if (k == 0 && t == 0) *loss_out = 0.0f;
}

// --- Kernel 2: fused normalize-x / MFMA GEMM / softmax / loss.
// v5 (resubmit; round-3 run was an infra flake, no data): combine v2's PROVEN
// store path (LDS-staged, 256-B-aligned shifted-window stores -> writes =
// ideal ~34 MB) with v3's occupancy win (64+10 KB LDS -> 2 blocks/CU,
// 16 waves/CU). Staging shrunk 4 KB -> 1.25 KB/wave by staging only the 4
// rows {4q+r} produced per softmax iteration and storing them immediately;
// the shifted window's lane-0 element (prev row col 63) rides in 4 carry
// registers (shuffle-filled). Rows 4/8/12 lane-0 dwords (cross-q ordering
// hole) are masked and patched post-loop from the final carries. Register
// pressure held at v3's proven-fitting level (2-deep prefetch, no p[4][4])
// to avoid scratch spill -- the suspected source of v3/v4's 246/400 MB
// write amplification.
__global__ __launch_bounds__(512, 4) void fused_kernel(
        const float* __restrict__ x,
        const unsigned* __restrict__ cb,
        const float* __restrict__ alphap,
        float* __restrict__ out) {                 // [0]=loss, [1..]=probs[N][64]
    __shared__ unsigned short ldsb[NK * DIM];      // 64 KB codebook
    __shared__ float sbuf[8][4 * 80];              // 10 KB staging: 4 rows/wave, stride 80
                                                   //  (stride 80 -> <=2-way banks, free)

    // stage codebook: 4096 16B-units; unit c6 of row r stored at (c6 ^ (r&7))
    for (int u = threadIdx.x; u < NK * DIM / 8; u += blockDim.x) {
        const int r = u >> 6, c6 = u & 63;
        const uint4 v = reinterpret_cast<const uint4*>(cb)[u];
        *reinterpret_cast<uint4*>(&ldsb[r * DIM + ((c6 ^ (r & 7)) << 3)]) = v;
    }
    __syncthreads();

    const float alpha = alphap[0];
    const int lane = threadIdx.x & 63;
    const int n = lane & 15;            // A-row / B-col / C-col lane index
    const int q = lane >> 4;            // quad
    const int sw = n & 7;               // LDS unit swizzle for this lane's B rows
    float* sb = sbuf[threadIdx.x >> 6];
    const int gw = (int)((blockIdx.x * blockDim.x + threadIdx.x) >> 6);
    const int nw = (int)((gridDim.x * blockDim.x) >> 6);

    const unsigned short* b_base = &ldsb[n * DIM];

    float lossa = 0.0f;

    for (int g = gw; g < NROWS / 16; g += nw) {
        const int row0 = g << 4;
        const float4* xp4 = reinterpret_cast<const float4*>(
            x + (size_t)(row0 + n) * DIM + (q << 3));
        f32x4 a0 = {0.f,0.f,0.f,0.f}, a1 = {0.f,0.f,0.f,0.f};
        f32x4 a2 = {0.f,0.f,0.f,0.f}, a3 = {0.f,0.f,0.f,0.f};
        float ss = 0.0f;

        // 2-deep register pipeline on x (v2's proven level of pressure)
        float4 c0 = xp4[0], c1 = xp4[1];
        float4 d0 = xp4[8], d1 = xp4[9];
#pragma unroll
        for (int t = 0; t < 16; t++) {
            float4 e0v, e1v;
            if (t < 14) { e0v = xp4[(t + 2) * 8]; e1v = xp4[(t + 2) * 8 + 1]; }
            ss += c0.x*c0.x + c0.y*c0.y + c0.z*c0.z + c0.w*c0.w
                + c1.x*c1.x + c1.y*c1.y + c1.z*c1.z + c1.w*c1.w;
            union { s16x8 v; unsigned u[4]; } A;
            A.u[0] = pk2(c0.x, c0.y); A.u[1] = pk2(c0.z, c0.w);
            A.u[2] = pk2(c1.x, c1.y); A.u[3] = pk2(c1.z, c1.w);
            const int off = (((t << 2) | q) ^ sw) << 3;   // swizzled 16B unit
            const s16x8 b0 = *reinterpret_cast<const s16x8*>(b_base + off);
            const s16x8 b1 = *reinterpret_cast<const s16x8*>(b_base + 16 * DIM + off);
            const s16x8 b2 = *reinterpret_cast<const s16x8*>(b_base + 32 * DIM + off);
            const s16x8 b3 = *reinterpret_cast<const s16x8*>(b_base + 48 * DIM + off);
            a0 = __builtin_amdgcn_mfma_f32_16x16x32_bf16(A.v, b0, a0, 0, 0, 0);
            a1 = __builtin_amdgcn_mfma_f32_16x16x32_bf16(A.v, b1, a1, 0, 0, 0);
            a2 = __builtin_amdgcn_mfma_f32_16x16x32_bf16(A.v, b2, a2, 0, 0, 0);
            a3 = __builtin_amdgcn_mfma_f32_16x16x32_bf16(A.v, b3, a3, 0, 0, 0);
            c0 = d0; c1 = d1; d0 = e0v; d1 = e1v;
        }

        // finish ||x_row||: lanes (q,n) hold partials of row n
        ss += __shfl_xor(ss, 16, 64);
        ss += __shfl_xor(ss, 32, 64);
        const float rnorm = 1.0f / fmaxf(sqrtf(ss), 1e-12f);

        // carries: col 63 of rows {4q + r} from the previous r-iteration
        float carry0 = 0.f, carry1 = 0.f, carry2 = 0.f, carry3 = 0.f;

#pragma unroll
        for (int r = 0; r < 4; r++) {
            // C row = q*4 + r; its rnorm lives at lanes with (lane&15) == q*4+r
            const float rn = __shfl(rnorm, (q << 2) + r, 64);
            const float i0 = a0[r] * rn, i1 = a1[r] * rn, i2 = a2[r] * rn, i3 = a3[r] * rn;
            const float z0 = i0 * alpha, z1 = i1 * alpha, z2 = i2 * alpha, z3 = i3 * alpha;
            float mx = fmaxf(fmaxf(z0, z1), fmaxf(z2, z3));
#pragma unroll
            for (int m = 1; m < 16; m <<= 1) mx = fmaxf(mx, __shfl_xor(mx, m, 64));
            const float e0 = __expf(z0 - mx), e1 = __expf(z1 - mx);
            const float e2 = __expf(z2 - mx), e3 = __expf(z3 - mx);
            float s  = e0 + e1 + e2 + e3;
            float sl = e0 * i0 + e1 * i1 + e2 * i2 + e3 * i3;   // loss uses pre-alpha ip
#pragma unroll
            for (int m = 1; m < 16; m <<= 1) {
                s  += __shfl_xor(s,  m, 64);
                sl += __shfl_xor(sl, m, 64);
            }
            const float inv = 1.0f / s;
            const float p0 = e0 * inv, p1 = e1 * inv, p2 = e2 * inv, p3 = e3 * inv;
            if (n == 0) lossa += sl * inv;      // one contribution per row

            // stage this iteration's 4 rows (row 4q+r into slot q)
            float* sq = sb + q * 80;
            sq[n]      = p0;
            sq[n + 16] = p1;
            sq[n + 32] = p2;
            sq[n + 48] = p3;

            // 4 aligned 256-B shifted-window stores: row k=4*qq+r,
            // out[(row0+k)*64+lane] = tile elem k*64+lane-1
#pragma unroll
            for (int qq = 0; qq < 4; qq++) {
                const float lv = sb[qq * 80 + (lane ? lane - 1 : 0)];
                const float cq = qq == 0 ? carry0 : qq == 1 ? carry1
                                : qq == 2 ? carry2 : carry3;
                const float v = lane ? lv : cq;
                if (r == 0) {
                    if (lane > 0)       // lane0: qq==0 from prev group; qq>0 patched
                        out[(size_t)(row0 + (qq << 2)) * 64 + lane] = v;
                } else {
                    out[(size_t)(row0 + (qq << 2) + r) * 64 + lane] = v;
                }
            }
            // update carries to this iteration's col-63 values (rows 4q+r)
            carry0 = __shfl(p3, 15, 64);
            carry1 = __shfl(p3, 31, 64);
            carry2 = __shfl(p3, 47, 64);
            carry3 = __shfl(p3, 63, 64);
        }

        // patches: after r=3, carries hold col63 of rows 3,7,11,15.
        // They are exactly the masked lane-0 dwords of rows 4,8,12 plus the
        // next group's first aligned slot (elem 1023 convention from v2).
        if (lane == 0) {
            out[(size_t)(row0 + 4)  * 64] = carry0;
            out[(size_t)(row0 + 8)  * 64] = carry1;
            out[(size_t)(row0 + 12) * 64] = carry2;
            out[(size_t)(row0 + 16) * 64] = carry3;
        }
    }

    // wave-level loss partials live in lanes 0,16,32,48
    lossa += __shfl_xor(lossa, 16, 64);
    lossa += __shfl_xor(lossa, 32, 64);
    if (lane == 0) atomicAdd(out, -lossa * (1.0f / NROWS));
}

extern "C" void kernel_launch(void* const* d_in, const int* in_sizes, int n_in,
                              void* d_out, int out_size, void* d_ws, size_t ws_size,
                              hipStream_t stream) {
    const float* x  = (const float*)d_in[0];
    const float* cl = (const float*)d_in[1];
    const float* al = (const float*)d_in[2];
    float* out = (float*)d_out;
    unsigned* cb = (unsigned*)d_ws;            // 64 KB bf16 codebook

    prep_kernel<<<dim3(NK), dim3(64), 0, stream>>>(cl, cb, out);
    fused_kernel<<<dim3(512), dim3(512), 0, stream>>>(x, cb, al, out);
}

// Round 5
// 419.542 us; speedup vs baseline: 1.4101x; 1.1817x over previous
//
#include <hip/hip_runtime.h>
#include <hip/hip_bf16.h>

#define NROWS 131072
#define DIM   512
#define NK    64

typedef __attribute__((ext_vector_type(4))) float f32x4;
typedef __attribute__((ext_vector_type(8))) short s16x8;

// pack two fp32 -> one dword of two bf16 (RNE), low half = first arg
static __device__ __forceinline__ unsigned pk2(float a, float b) {
    union { __hip_bfloat162 h; unsigned u; } cv;
    cv.h = __float22bfloat162_rn(make_float2(a, b));
    return cv.u;
}

// --- Kernel 1: L2-normalize clusters (fp32) -> bf16 codebook in ws; zero loss slot.
__global__ void prep_kernel(const float* __restrict__ cl,
                            unsigned* __restrict__ cb,    // bf16[64][512] as dwords
                            float* __restrict__ loss_out) {
    const int k = blockIdx.x, t = threadIdx.x;
    const float4* rp = reinterpret_cast<const float4*>(cl + k * DIM);
    float4 f0 = rp[2 * t], f1 = rp[2 * t + 1];
    float ss = f0.x*f0.x + f0.y*f0.y + f0.z*f0.z + f0.w*f0.w
             + f1.x*f1.x + f1.y*f1.y + f1.z*f1.z + f1.w*f1.w;
#pragma unroll
    for (int m = 1; m < 64; m <<= 1) ss += __shfl_xor(ss, m, 64);
    const float rn = 1.0f / fmaxf(sqrtf(ss), 1e-12f);
    uint4 o;
    o.x = pk2(f0.x * rn, f0.y * rn);
    o.y = pk2(f0.z * rn, f0.w * rn);
    o.z = pk2(f1.x * rn, f1.y * rn);
    o.w = pk2(f1.z * rn, f1.w * rn);
    reinterpret_cast<uint4*>(cb + (size_t)k * (DIM / 2))[t] = o;
    if (k == 0 && t == 0) *loss_out = 0.0f;
}

// --- Kernel 2: fused normalize-x / MFMA GEMM / softmax / loss.
// v6 = v5 with ONE change: __launch_bounds__(512, 2) instead of (512, 4).
// Rationale: v3/v4/v5 all pinned VGPR_Count at exactly 64 under (512,4) and
// all showed 200-370 MB of HBM write amplification regardless of store
// pattern (v5's aligned LDS-staged stores changed nothing vs v3's misaligned
// direct stores). Diagnosis: the (512,4) bound clamps the allocator to 64
// arch-VGPRs, far below the ~100-register live set -> per-t-loop scratch
// spill -> L2/L3 thrash under the 268 MB x stream -> HBM writebacks.
// The 74 KB LDS footprint already caps residency at 2 blocks/CU, so the
// launch bound is NOT needed for occupancy: with a 256-VGPR budget the
// allocator should land ~96-128 (16 waves/CU, zero spill); worst case
// >128 falls back to v2's 8 waves/CU with no spill (~150 us, bounded).
__global__ __launch_bounds__(512, 2) void fused_kernel(
        const float* __restrict__ x,
        const unsigned* __restrict__ cb,
        const float* __restrict__ alphap,
        float* __restrict__ out) {                 // [0]=loss, [1..]=probs[N][64]
    __shared__ unsigned short ldsb[NK * DIM];      // 64 KB codebook
    __shared__ float sbuf[8][4 * 80];              // 10 KB staging: 4 rows/wave, stride 80
                                                   //  (stride 80 -> <=2-way banks, free)

    // stage codebook: 4096 16B-units; unit c6 of row r stored at (c6 ^ (r&7))
    for (int u = threadIdx.x; u < NK * DIM / 8; u += blockDim.x) {
        const int r = u >> 6, c6 = u & 63;
        const uint4 v = reinterpret_cast<const uint4*>(cb)[u];
        *reinterpret_cast<uint4*>(&ldsb[r * DIM + ((c6 ^ (r & 7)) << 3)]) = v;
    }
    __syncthreads();

    const float alpha = alphap[0];
    const int lane = threadIdx.x & 63;
    const int n = lane & 15;            // A-row / B-col / C-col lane index
    const int q = lane >> 4;            // quad
    const int sw = n & 7;               // LDS unit swizzle for this lane's B rows
    float* sb = sbuf[threadIdx.x >> 6];
    const int gw = (int)((blockIdx.x * blockDim.x + threadIdx.x) >> 6);
    const int nw = (int)((gridDim.x * blockDim.x) >> 6);

    const unsigned short* b_base = &ldsb[n * DIM];

    float lossa = 0.0f;

    for (int g = gw; g < NROWS / 16; g += nw) {
        const int row0 = g << 4;
        const float4* xp4 = reinterpret_cast<const float4*>(
            x + (size_t)(row0 + n) * DIM + (q << 3));
        f32x4 a0 = {0.f,0.f,0.f,0.f}, a1 = {0.f,0.f,0.f,0.f};
        f32x4 a2 = {0.f,0.f,0.f,0.f}, a3 = {0.f,0.f,0.f,0.f};
        float ss = 0.0f;

        // 2-deep register pipeline on x
        float4 c0 = xp4[0], c1 = xp4[1];
        float4 d0 = xp4[8], d1 = xp4[9];
#pragma unroll
        for (int t = 0; t < 16; t++) {
            float4 e0v, e1v;
            if (t < 14) { e0v = xp4[(t + 2) * 8]; e1v = xp4[(t + 2) * 8 + 1]; }
            ss += c0.x*c0.x + c0.y*c0.y + c0.z*c0.z + c0.w*c0.w
                + c1.x*c1.x + c1.y*c1.y + c1.z*c1.z + c1.w*c1.w;
            union { s16x8 v; unsigned u[4]; } A;
            A.u[0] = pk2(c0.x, c0.y); A.u[1] = pk2(c0.z, c0.w);
            A.u[2] = pk2(c1.x, c1.y); A.u[3] = pk2(c1.z, c1.w);
            const int off = (((t << 2) | q) ^ sw) << 3;   // swizzled 16B unit
            const s16x8 b0 = *reinterpret_cast<const s16x8*>(b_base + off);
            const s16x8 b1 = *reinterpret_cast<const s16x8*>(b_base + 16 * DIM + off);
            const s16x8 b2 = *reinterpret_cast<const s16x8*>(b_base + 32 * DIM + off);
            const s16x8 b3 = *reinterpret_cast<const s16x8*>(b_base + 48 * DIM + off);
            a0 = __builtin_amdgcn_mfma_f32_16x16x32_bf16(A.v, b0, a0, 0, 0, 0);
            a1 = __builtin_amdgcn_mfma_f32_16x16x32_bf16(A.v, b1, a1, 0, 0, 0);
            a2 = __builtin_amdgcn_mfma_f32_16x16x32_bf16(A.v, b2, a2, 0, 0, 0);
            a3 = __builtin_amdgcn_mfma_f32_16x16x32_bf16(A.v, b3, a3, 0, 0, 0);
            c0 = d0; c1 = d1; d0 = e0v; d1 = e1v;
        }

        // finish ||x_row||: lanes (q,n) hold partials of row n
        ss += __shfl_xor(ss, 16, 64);
        ss += __shfl_xor(ss, 32, 64);
        const float rnorm = 1.0f / fmaxf(sqrtf(ss), 1e-12f);

        // carries: col 63 of rows {4q + r} from the previous r-iteration
        float carry0 = 0.f, carry1 = 0.f, carry2 = 0.f, carry3 = 0.f;

#pragma unroll
        for (int r = 0; r < 4; r++) {
            // C row = q*4 + r; its rnorm lives at lanes with (lane&15) == q*4+r
            const float rn = __shfl(rnorm, (q << 2) + r, 64);
            const float i0 = a0[r] * rn, i1 = a1[r] * rn, i2 = a2[r] * rn, i3 = a3[r] * rn;
            const float z0 = i0 * alpha, z1 = i1 * alpha, z2 = i2 * alpha, z3 = i3 * alpha;
            float mx = fmaxf(fmaxf(z0, z1), fmaxf(z2, z3));
#pragma unroll
            for (int m = 1; m < 16; m <<= 1) mx = fmaxf(mx, __shfl_xor(mx, m, 64));
            const float e0 = __expf(z0 - mx), e1 = __expf(z1 - mx);
            const float e2 = __expf(z2 - mx), e3 = __expf(z3 - mx);
            float s  = e0 + e1 + e2 + e3;
            float sl = e0 * i0 + e1 * i1 + e2 * i2 + e3 * i3;   // loss uses pre-alpha ip
#pragma unroll
            for (int m = 1; m < 16; m <<= 1) {
                s  += __shfl_xor(s,  m, 64);
                sl += __shfl_xor(sl, m, 64);
            }
            const float inv = 1.0f / s;
            const float p0 = e0 * inv, p1 = e1 * inv, p2 = e2 * inv, p3 = e3 * inv;
            if (n == 0) lossa += sl * inv;      // one contribution per row

            // stage this iteration's 4 rows (row 4q+r into slot q)
            float* sq = sb + q * 80;
            sq[n]      = p0;
            sq[n + 16] = p1;
            sq[n + 32] = p2;
            sq[n + 48] = p3;

            // 4 aligned 256-B shifted-window stores: row k=4*qq+r,
            // out[(row0+k)*64+lane] = tile elem k*64+lane-1
#pragma unroll
            for (int qq = 0; qq < 4; qq++) {
                const float lv = sb[qq * 80 + (lane ? lane - 1 : 0)];
                const float cq = qq == 0 ? carry0 : qq == 1 ? carry1
                                : qq == 2 ? carry2 : carry3;
                const float v = lane ? lv : cq;
                if (r == 0) {
                    if (lane > 0)       // lane0: qq==0 from prev group; qq>0 patched
                        out[(size_t)(row0 + (qq << 2)) * 64 + lane] = v;
                } else {
                    out[(size_t)(row0 + (qq << 2) + r) * 64 + lane] = v;
                }
            }
            // update carries to this iteration's col-63 values (rows 4q+r)
            carry0 = __shfl(p3, 15, 64);
            carry1 = __shfl(p3, 31, 64);
            carry2 = __shfl(p3, 47, 64);
            carry3 = __shfl(p3, 63, 64);
        }

        // patches: after r=3, carries hold col63 of rows 3,7,11,15.
        // They are exactly the masked lane-0 dwords of rows 4,8,12 plus the
        // next group's first aligned slot (elem 1023 convention from v2).
        if (lane == 0) {
            out[(size_t)(row0 + 4)  * 64] = carry0;
            out[(size_t)(row0 + 8)  * 64] = carry1;
            out[(size_t)(row0 + 12) * 64] = carry2;
            out[(size_t)(row0 + 16) * 64] = carry3;
        }
    }

    // wave-level loss partials live in lanes 0,16,32,48
    lossa += __shfl_xor(lossa, 16, 64);
    lossa += __shfl_xor(lossa, 32, 64);
    if (lane == 0) atomicAdd(out, -lossa * (1.0f / NROWS));
}

extern "C" void kernel_launch(void* const* d_in, const int* in_sizes, int n_in,
                              void* d_out, int out_size, void* d_ws, size_t ws_size,
                              hipStream_t stream) {
    const float* x  = (const float*)d_in[0];
    const float* cl = (const float*)d_in[1];
    const float* al = (const float*)d_in[2];
    float* out = (float*)d_out;
    unsigned* cb = (unsigned*)d_ws;            // 64 KB bf16 codebook

    prep_kernel<<<dim3(NK), dim3(64), 0, stream>>>(cl, cb, out);
    fused_kernel<<<dim3(512), dim3(512), 0, stream>>>(x, cb, al, out);
}